// Round 12
// baseline (354.914 us; speedup 1.0000x reference)
//
#include <hip/hip_runtime.h>
#include <hip/hip_fp16.h>

// EMD approx-match (auction) + match_cost, fully fused, ONE normal launch.
// R26: R25 (289us fused, VALU-issue 188us, stall 101us) proved skip deletes
// work but its per-phase work VARIANCE turns into barrier stall -- and at
// 1 block/CU (R23 geometry) every barrier wait idles the whole CU. This
// round: 512 blocks x 512 threads (64 blocks/batch, ROWS=32), LDS 64KB
// dynamic + ~3.3KB static = ~68KB -> TWO blocks per CU (137 < 160KB).
// Dispatch places bids 0-255 (batches 0-3) and 256-511 (batches 4-7) on the
// same CUs -> co-resident blocks are from DIFFERENT batches with independent
// barriers: one computes while the other waits. Sort+skip+spread+interleave
// unchanged (half-spread: block owns sorted 16-row/16-m tiles {bslot,
// bslot+64}). Failure mode benign: if 1/CU only, batches 0-3 then 4-7 run
// sequentially (each batch fully co-resident -> no deadlock, ~neutral).

#define BATCH 8
#define NPTS 2048
#define MPTS 2048
#define BLOCK 512
#define ROWS 32
#define BLOCKS_PER_BATCH 64
#define NSUB 8
#define SUBTGT (BLOCKS_PER_BATCH / NSUB)   // 8
#define NSYNC 21
#define PAD 16                             // dwords per 64B line
#define SKIP_THR (-130.0f)
#define LOG2E 1.44269504088896340736f

__device__ __forceinline__ float fast_exp2(float x) {
  return __builtin_amdgcn_exp2f(x);     // v_exp_f32
}
__device__ __forceinline__ float fast_sqrt(float a) {
  return __builtin_amdgcn_sqrtf(a);     // v_sqrt_f32
}
__device__ __forceinline__ float packh2(float c, float r) {
  __half2 h = __halves2half2(__float2half_rn(c), __float2half_rn(r));
  return __builtin_bit_cast(float, h);
}

// ---- agent-scope coherent access helpers (bypass non-coherent XCD L2) ----
__device__ __forceinline__ float cohLoad(const float* p) {
  return __hip_atomic_load((float*)p, __ATOMIC_RELAXED,
                           __HIP_MEMORY_SCOPE_AGENT);
}
__device__ __forceinline__ void cohStore(float* p, float v) {
  __hip_atomic_store(p, v, __ATOMIC_RELAXED, __HIP_MEMORY_SCOPE_AGENT);
}

// Per-batch grid barrier, two-level: 8 sub-counters (own 64B line each),
// 8 arrivals per sub. Absolute target (counters memset each launch).
__device__ __forceinline__ void batch_barrier(unsigned* base, int bid) {
  __syncthreads();
  if (threadIdx.x == 0) {
    __hip_atomic_fetch_add(base + (bid & (NSUB - 1)) * PAD, 1u,
                           __ATOMIC_RELAXED, __HIP_MEMORY_SCOPE_AGENT);
  }
  if (threadIdx.x < NSUB) {
    int guard = 0;
    while (__hip_atomic_load(base + threadIdx.x * PAD, __ATOMIC_RELAXED,
                             __HIP_MEMORY_SCOPE_AGENT) < (unsigned)SUBTGT) {
      __builtin_amdgcn_s_sleep(2);
      if (++guard > (1 << 22)) break;
    }
  }
  asm volatile("" ::: "memory");
  __syncthreads();
}

// Wave-wide x-interval of per-lane values (min over lo, max over hi).
__device__ __forceinline__ void wave_interval(float& lo, float& hi) {
#pragma unroll
  for (int s = 1; s < 64; s <<= 1) {
    lo = fminf(lo, __shfl_xor(lo, s, 64));
    hi = fmaxf(hi, __shfl_xor(hi, s, 64));
  }
}

// Load 8 consecutive sorted points from LDS float4 array.
__device__ __forceinline__ void load8L(const float4* sA, int r0,
                                       float* x, float* y, float* z) {
#pragma unroll
  for (int j = 0; j < 8; ++j) {
    float4 v = sA[r0 + j];
    x[j] = v.x; y[j] = v.y; z[j] = v.z;
  }
}

// Transposed t1 sweep + owner fusion, LDS-resident sorted clouds.
// Owned m (half-spread): gm = (bslot + (m_idx>>4)*64)*16 + (m_idx&15).
// Wave spans 4 CONTIGUOUS sorted m's (tight interval). n iterated in 32
// chunks of 64 sorted points; wave-uniform skip via sTileN interval.
__device__ __forceinline__ void sweep2T_fuse(
    float nc, int tid, int bslot, const float* rsG, float* wpB,
    float4* sA, const float4* sP, const float2* sTileN, float* sRR) {
  // stage rs (sorted order) into sA[].w
#pragma unroll
  for (int k = 0; k < 4; ++k)
    sA[tid + k * 512].w = cohLoad(rsG + tid + k * 512);
  __syncthreads();
  const int m_idx = tid >> 4, c = tid & 15;
  const int gm = (bslot + (m_idx >> 4) * 64) * 16 + (m_idx & 15);
  const float4 pm = sP[gm];
  float mlo = pm.x, mhi = pm.x;
  wave_interval(mlo, mhi);
  float part = 0.f;
  for (int ch = 0; ch < 32; ++ch) {
    float2 tn = sTileN[ch];
    float gap = fmaxf(0.f, fmaxf(tn.x - mhi, mlo - tn.y));
    if (nc * gap * gap < SKIP_THR) continue;   // all 64 pairs underflow
    int nb = ch * 64 + c;
#pragma unroll
    for (int j = 0; j < 4; ++j) {
      float4 v = sA[nb + 16 * j];
      float dx = v.x - pm.x, dy = v.y - pm.y, dz = v.z - pm.z;
      float d2 = __builtin_fmaf(dx, dx, __builtin_fmaf(dy, dy, dz * dz));
      part = __builtin_fmaf(fast_exp2(nc * d2), v.w, part);
    }
  }
  part += __shfl_xor(part, 1, 64);
  part += __shfl_xor(part, 2, 64);
  part += __shfl_xor(part, 4, 64);
  part += __shfl_xor(part, 8, 64);
  if (c == 0) {
    float t1v = part;
    float rr = sRR[m_idx];
    float colsum = rr * t1v;
    float cs = fminf(rr / (colsum + 1e-9f), 1.0f);
    float ccv = rr * cs;
    float rn = fmaxf(rr - colsum * cs, 0.f);
    cohStore(wpB + gm, packh2(ccv, rn));
    sRR[m_idx] = rn;
  }
}

__global__ __launch_bounds__(BLOCK) void emd_fused_kernel(
    const float* __restrict__ xyz1, const float* __restrict__ xyz2,
    float* __restrict__ out, float* __restrict__ rowscaleG,
    float* __restrict__ wPack, float* __restrict__ R9acc,
    float* __restrict__ t9, float* __restrict__ outAcc,
    unsigned* __restrict__ ctr) {
  extern __shared__ __align__(16) float4 sDyn[];
  float4* sA = sDyn;                       // sorted xyz1; w = rs (per sweep2T)
  float4* sP = sDyn + 2048;                // sorted xyz2; w = level payload
  unsigned* sKeyA = (unsigned*)(sDyn + 2048);        // aliases sP (sort phase)
  unsigned* sKeyB = ((unsigned*)(sDyn + 2048)) + 2048;

  __shared__ float sRedS[ROWS * 4];
  __shared__ float sRedC[ROWS * 4];
  __shared__ float sRedR[ROWS * 4];
  __shared__ float sCost[ROWS];
  __shared__ float sRowScale[ROWS];        // persistent across levels (local)
  __shared__ float sRemainL[ROWS];         // persistent across levels (local)
  __shared__ float sRR[ROWS];              // owner's rr slice (local)
  __shared__ float2 sTileM[128];           // 16-m-tile x-intervals (sorted)
  __shared__ float2 sTileN[32];            // 64-n-chunk x-intervals (sorted)

  const int tid = threadIdx.x;
  const int bid = blockIdx.x;
  const int b = bid >> 6;
  const int bslot = bid & 63;
  const bool desig = bslot == 0;
  const int wave = tid >> 6, lane = tid & 63;
  const int mq = wave & 3;                 // m-partition (stride-4 interleave)
  const int rh = wave >> 2;                // row-group (half-spread, 0/1)
  const size_t bM = (size_t)b * MPTS;
  float costAcc = 0.f;                     // meaningful on tid==0
  // half-spread map: group g (0/1) -> global sorted base index
#define GB(g) ((bslot + (g) * 64) * 16)

  float* rsG = rowscaleG + (size_t)b * NPTS;
  float* wpB = wPack + bM;
  const float* p1 = xyz1 + (size_t)b * NPTS * 3;
  const float* p2 = xyz2 + bM * 3;
#define CTRB(s) (ctr + (size_t)(((s) * BATCH + b) * NSUB) * PAD)

  // ---- deterministic per-block sort of both clouds by x (identical in
  //      every block -> no cross-block traffic). Key = top-21 orderable
  //      float bits | 11-bit idx. ----
  for (int e = tid; e < 2048; e += BLOCK) {
    unsigned u1 = __builtin_bit_cast(unsigned, p1[e * 3]);
    u1 = (u1 & 0x80000000u) ? ~u1 : (u1 | 0x80000000u);
    sKeyA[e] = (u1 & 0xFFFFF800u) | (unsigned)e;
    unsigned u2 = __builtin_bit_cast(unsigned, p2[e * 3]);
    u2 = (u2 & 0x80000000u) ? ~u2 : (u2 | 0x80000000u);
    sKeyB[e] = (u2 & 0xFFFFF800u) | (unsigned)e;
  }
  for (unsigned k = 2; k <= 2048; k <<= 1) {
    for (unsigned j = k >> 1; j > 0; j >>= 1) {
      __syncthreads();
      for (int e = tid; e < 2048; e += BLOCK) {
        int l = e ^ (int)j;
        if (l > e) {
          bool up = ((e & (int)k) == 0);
          unsigned a = sKeyA[e], bv = sKeyA[l];
          if ((a > bv) == up) { sKeyA[e] = bv; sKeyA[l] = a; }
          unsigned a2 = sKeyB[e], b2 = sKeyB[l];
          if ((a2 > b2) == up) { sKeyB[e] = b2; sKeyB[l] = a2; }
        }
      }
    }
  }
  __syncthreads();
  {
    int iA[4], iB[4];
#pragma unroll
    for (int k = 0; k < 4; ++k) {
      iA[k] = sKeyA[tid + k * 512] & 2047;
      iB[k] = sKeyB[tid + k * 512] & 2047;
    }
    __syncthreads();                       // keys consumed; sP region free
#pragma unroll
    for (int k = 0; k < 4; ++k) {
      int e = tid + k * 512;
      sA[e] = make_float4(p1[iA[k]*3], p1[iA[k]*3+1], p1[iA[k]*3+2], 0.f);
      sP[e] = make_float4(p2[iB[k]*3], p2[iB[k]*3+1], p2[iB[k]*3+2], 0.f);
    }
  }
  if (tid < ROWS) sRR[tid] = 1.0f;
  if (desig && tid == 0) {
    cohStore(R9acc + b * PAD, 0.f);
    cohStore(t9 + b * PAD, 0.f);
    cohStore(outAcc + b * PAD, 0.f);
  }
  __syncthreads();
  // tile interval metadata (exact min/max; robust to truncated-key ties)
  if (tid < 128) {
    float lo = sP[tid * 16].x, hi = lo;
    for (int i = 1; i < 16; ++i) {
      float x = sP[tid * 16 + i].x;
      lo = fminf(lo, x); hi = fmaxf(hi, x);
    }
    sTileM[tid] = make_float2(lo, hi);
  } else if (tid < 160) {
    int t = tid - 128;
    float lo = sA[t * 64].x, hi = lo;
    for (int i = 1; i < 64; ++i) {
      float x = sA[t * 64 + i].x;
      lo = fminf(lo, x); hi = fmaxf(hi, x);
    }
    sTileN[t] = make_float2(lo, hi);
  }
  __syncthreads();

  // ---- A0: rowscale_0 (skip via interleaved 32-m chunks) ----
  const float nc0 = -16384.0f * LOG2E;
  {
    const int ph = lane >> 1, rg = lane & 1;
    float x1a[8], y1a[8], z1a[8], acc[8];
    load8L(sA, GB(rh) + rg * 8, x1a, y1a, z1a);
#pragma unroll
    for (int j = 0; j < 8; ++j) acc[j] = 0.f;
    float rlo = x1a[0], rhi = x1a[0];
#pragma unroll
    for (int j = 1; j < 8; ++j) {
      rlo = fminf(rlo, x1a[j]); rhi = fmaxf(rhi, x1a[j]);
    }
    wave_interval(rlo, rhi);
    for (int it = 0; it < 16; ++it) {
      int t2 = it * 4 + mq;               // 32-m chunk, stride-4 interleave
      float lo = sTileM[2 * t2].x, hi = sTileM[2 * t2 + 1].y;
      float gap = fmaxf(0.f, fmaxf(lo - rhi, rlo - hi));
      if (nc0 * gap * gap < SKIP_THR) continue;
      float4 v = sP[t2 * 32 + ph];
#pragma unroll
      for (int j = 0; j < 8; ++j) {
        float dx = x1a[j] - v.x, dy = y1a[j] - v.y, dz = z1a[j] - v.z;
        float d2 = __builtin_fmaf(dx, dx, __builtin_fmaf(dy, dy, dz * dz));
        acc[j] += fast_exp2(nc0 * d2);
      }
    }
#pragma unroll
    for (int j = 0; j < 8; ++j) {
      acc[j] += __shfl_xor(acc[j], 2, 64);
      acc[j] += __shfl_xor(acc[j], 4, 64);
      acc[j] += __shfl_xor(acc[j], 8, 64);
      acc[j] += __shfl_xor(acc[j], 16, 64);
      acc[j] += __shfl_xor(acc[j], 32, 64);
    }
    if (lane < 2) {
#pragma unroll
      for (int j = 0; j < 8; ++j)
        sRedS[(rh * 16 + rg * 8 + j) * 4 + mq] = acc[j];
    }
    __syncthreads();
    if (tid < ROWS) {
      float s = sRedS[tid * 4] + sRedS[tid * 4 + 1] + sRedS[tid * 4 + 2] +
                sRedS[tid * 4 + 3];
      float rs = 1.0f / (s + 1e-9f);
      sRowScale[tid] = rs;
      cohStore(rsG + GB(tid >> 4) + (tid & 15), rs);
    }
  }
  batch_barrier(CTRB(0), bid);          // rs_0 + init zeroes visible
  sweep2T_fuse(nc0, tid, bslot, rsG, wpB, sA, sP, sTileN, sRR);  // -> wPack_0
  batch_barrier(CTRB(1), bid);          // wPack_0 visible

  // ---- persistent CA row fragment (sorted coords from LDS) ----
  float x1[4], y1[4], z1[4];
  {
    int r0 = GB(rh) + (lane & 3) * 4;
#pragma unroll
    for (int j = 0; j < 4; ++j) {
      float4 v = sA[r0 + j];
      x1[j] = v.x; y1[j] = v.y; z1[j] = v.z;
    }
  }
  float rlo = fminf(fminf(x1[0], x1[1]), fminf(x1[2], x1[3]));
  float rhi = fmaxf(fmaxf(x1[0], x1[1]), fmaxf(x1[2], x1[3]));
  wave_interval(rlo, rhi);
  const int phc = lane >> 2, rgc = lane & 3;

  float nc2 = -4096.0f * LOG2E;   // levels[l+1]*LOG2E; exact /4 per level
  for (int l = 0; l < 9; ++l) {
    const bool LAST = (l == 8);
    // -- staging: sP[m].w = wPack_l[m] --
#pragma unroll
    for (int k = 0; k < 4; ++k) {
      int m = tid + k * 512;
      sP[m].w = cohLoad(wpB + m);
    }
    __syncthreads();
    // -- sweep1: cost(l) + remainL + rowscale(l+1). e1 = e2^4 (exact).
    //    m-tiles stride-4 interleaved across mq; skip per 16-m tile. --
    float accS[4] = {0.f, 0.f, 0.f, 0.f};
    float accC[4] = {0.f, 0.f, 0.f, 0.f};
    float accR[4] = {0.f, 0.f, 0.f, 0.f};
    for (int it = 0; it < 32; ++it) {
      int t = it * 4 + mq;                // stride-4 interleave
      float2 tm = sTileM[t];
      float gap = fmaxf(0.f, fmaxf(tm.x - rhi, rlo - tm.y));
      if (nc2 * gap * gap < SKIP_THR) continue;
      float4 v = sP[t * 16 + phc];
      __half2 h = __builtin_bit_cast(__half2, v.w);
      float cc = __low2float(h);
      float rr = __high2float(h);
#pragma unroll
      for (int j = 0; j < 4; ++j) {
        float dx = x1[j] - v.x, dy = y1[j] - v.y, dz = z1[j] - v.z;
        float d2 = __builtin_fmaf(dx, dx, __builtin_fmaf(dy, dy, dz * dz));
        float sq = fast_sqrt(d2);
        float e2 = fast_exp2(nc2 * d2);
        float e2s = e2 * e2;
        float e1 = e2s * e2s;   // exp(levels[l]*d2); at LAST -> exp(-0.25 d2)
        float t2 = e1 * cc;
        accS[j] += t2;
        accC[j] = __builtin_fmaf(t2, sq, accC[j]);
        accR[j] = __builtin_fmaf(e2, rr, accR[j]);
      }
    }
#pragma unroll
    for (int j = 0; j < 4; ++j) {
      accS[j] += __shfl_xor(accS[j], 4, 64);
      accS[j] += __shfl_xor(accS[j], 8, 64);
      accS[j] += __shfl_xor(accS[j], 16, 64);
      accS[j] += __shfl_xor(accS[j], 32, 64);
      accC[j] += __shfl_xor(accC[j], 4, 64);
      accC[j] += __shfl_xor(accC[j], 8, 64);
      accC[j] += __shfl_xor(accC[j], 16, 64);
      accC[j] += __shfl_xor(accC[j], 32, 64);
      accR[j] += __shfl_xor(accR[j], 4, 64);
      accR[j] += __shfl_xor(accR[j], 8, 64);
      accR[j] += __shfl_xor(accR[j], 16, 64);
      accR[j] += __shfl_xor(accR[j], 32, 64);
    }
    if (lane < 4) {
#pragma unroll
      for (int j = 0; j < 4; ++j) {
        int row = rh * 16 + rgc * 4 + j;
        sRedS[row * 4 + mq] = accS[j];
        sRedC[row * 4 + mq] = accC[j];
        sRedR[row * 4 + mq] = accR[j];
      }
    }
    __syncthreads();
    if (tid < ROWS) {
      float S2 = sRedS[tid * 4] + sRedS[tid * 4 + 1] + sRedS[tid * 4 + 2] +
                 sRedS[tid * 4 + 3];
      float C = sRedC[tid * 4] + sRedC[tid * 4 + 1] + sRedC[tid * 4 + 2] +
                sRedC[tid * 4 + 3];
      float R = sRedR[tid * 4] + sRedR[tid * 4 + 1] + sRedR[tid * 4 + 2] +
                sRedR[tid * 4 + 3];
      if (LAST) R = cohLoad(R9acc + b * PAD);   // sum_m rr_9 (e == 1)
      float rs = sRowScale[tid];
      float rl = (l == 0) ? 1.0f : sRemainL[tid];
      float rlN = fmaxf(rl - rs * S2, 0.f);
      sRemainL[tid] = rlN;
      float rsN = rlN / (R + 1e-9f);
      sRowScale[tid] = rsN;
      if (!LAST) cohStore(rsG + GB(tid >> 4) + (tid & 15), rsN);
      sCost[tid] = rs * C;
    }
    __syncthreads();
    if (tid == 0) {
      float t = 0.f;
#pragma unroll
      for (int i = 0; i < ROWS; ++i) t += sCost[i];
      costAcc += t;
      if (LAST) {
        float r = 0.f;
#pragma unroll
        for (int i = 0; i < ROWS; ++i) r += sRowScale[i];
        atomicAdd(t9 + b * PAD, r);       // one per block, padded line
      }
    }
    if (!LAST) {
      batch_barrier(CTRB(2 + 2 * l), bid);    // rsN_{l+1} visible
      sweep2T_fuse(nc2, tid, bslot, rsG, wpB, sA, sP, sTileN, sRR);
      if (l == 7) {          // R9 = sum_m rr_9: block partial, one atomic
        __syncthreads();
        if (tid == 0) {
          float r9 = 0.f;
#pragma unroll
          for (int i = 0; i < ROWS; ++i) r9 += sRR[i];
          atomicAdd(R9acc + b * PAD, r9);
        }
      }
      batch_barrier(CTRB(3 + 2 * l), bid);    // wPack_{l+1} (+R9acc) visible
      nc2 *= 0.25f;
    }
  }
  batch_barrier(CTRB(18), bid);               // t9 complete

  // ---- C9 owner publish: w[m] from full-precision rr_9 + t9 ----
  if (tid < ROWS) {
    float rr = sRR[tid];
    float t1s = cohLoad(t9 + b * PAD);
    float w = rr * fminf(rr / (__builtin_fmaf(rr, t1s, 1e-9f)), 1.0f);
    cohStore(wpB + GB(tid >> 4) + (tid & 15), w); // full float (old C9 match)
  }
  batch_barrier(CTRB(19), bid);               // w visible

  // ---- C9 (lvl=0): cost with unscaled sorted coords (no skip: no exp) ----
  {
#pragma unroll
    for (int k = 0; k < 4; ++k) {
      int m = tid + k * 512;
      sP[m].w = cohLoad(wpB + m);
    }
    __syncthreads();
    const int ph = lane >> 1, rg = lane & 1;
    float x1a[8], y1a[8], z1a[8], acc[8];
    load8L(sA, GB(rh) + rg * 8, x1a, y1a, z1a);
#pragma unroll
    for (int j = 0; j < 8; ++j) acc[j] = 0.f;
    const int mb = mq * 512 + ph;
#pragma unroll 2
    for (int it = 0; it < 16; ++it) {
      float4 v = sP[mb + it * 32];
#pragma unroll
      for (int j = 0; j < 8; ++j) {
        float dx = x1a[j] - v.x, dy = y1a[j] - v.y, dz = z1a[j] - v.z;
        float d2 = __builtin_fmaf(dx, dx, __builtin_fmaf(dy, dy, dz * dz));
        acc[j] = __builtin_fmaf(fast_sqrt(d2), v.w, acc[j]);
      }
    }
#pragma unroll
    for (int j = 0; j < 8; ++j) {
      acc[j] += __shfl_xor(acc[j], 2, 64);
      acc[j] += __shfl_xor(acc[j], 4, 64);
      acc[j] += __shfl_xor(acc[j], 8, 64);
      acc[j] += __shfl_xor(acc[j], 16, 64);
      acc[j] += __shfl_xor(acc[j], 32, 64);
    }
    if (lane < 2) {
#pragma unroll
      for (int j = 0; j < 8; ++j)
        sRedS[(rh * 16 + rg * 8 + j) * 4 + mq] = acc[j];
    }
    __syncthreads();
    if (tid < ROWS) {
      float C = sRedS[tid * 4] + sRedS[tid * 4 + 1] + sRedS[tid * 4 + 2] +
                sRedS[tid * 4 + 3];
      sCost[tid] = sRowScale[tid] * C;
    }
    __syncthreads();
    if (tid == 0) {
      float t = 0.f;
#pragma unroll
      for (int i = 0; i < ROWS; ++i) t += sCost[i];
      costAcc += t;
      atomicAdd(outAcc + b * PAD, costAcc);   // ONE atomic per block total
    }
  }
  batch_barrier(CTRB(20), bid);               // outAcc complete
  if (desig && tid == 0) out[b] = cohLoad(outAcc + b * PAD);
#undef CTRB
#undef GB
}

// ---------------------------------------------------------------------------
extern "C" void kernel_launch(void* const* d_in, const int* in_sizes, int n_in,
                              void* d_out, int out_size, void* d_ws, size_t ws_size,
                              hipStream_t stream) {
  const float* xyz1 = (const float*)d_in[0];
  const float* xyz2 = (const float*)d_in[1];
  float* out = (float*)d_out;
  float* ws = (float*)d_ws;

  const int BM = BATCH * MPTS;               // 16384
  float* rowscaleG = ws;                     // BM
  float* wPack     = ws + BM;                // BM
  float* R9acc     = ws + 2 * BM;            // BATCH*PAD
  float* t9        = ws + 2 * BM + BATCH * PAD;      // BATCH*PAD
  float* outAcc    = ws + 2 * BM + 2 * BATCH * PAD;  // BATCH*PAD
  unsigned* ctr    = (unsigned*)(ws + 2 * BM + 3 * BATCH * PAD);
  // ctr: NSYNC*BATCH*NSUB*PAD u32 = 21*8*8*16 = 21504 u32 (~86KB)

  static bool attrSet = false;
  if (!attrSet) {
    hipFuncSetAttribute((const void*)emd_fused_kernel,
                        hipFuncAttributeMaxDynamicSharedMemorySize, 65536);
    attrSet = true;
  }

  hipMemsetAsync(ctr, 0, (size_t)NSYNC * BATCH * NSUB * PAD * sizeof(unsigned),
                 stream);

  void* args[] = {(void*)&xyz1, (void*)&xyz2, (void*)&out, (void*)&rowscaleG,
                  (void*)&wPack, (void*)&R9acc, (void*)&t9, (void*)&outAcc,
                  (void*)&ctr};
  hipLaunchKernel((const void*)emd_fused_kernel,
                  dim3(BATCH * (NPTS / ROWS)), dim3(BLOCK), args,
                  65536, stream);
}

// Round 14
// 314.630 us; speedup vs baseline: 1.1280x; 1.1280x over previous
//
#include <hip/hip_runtime.h>
#include <hip/hip_fp16.h>

// EMD approx-match (auction) + match_cost, fully fused, ONE launch, NO memset.
// R28 = R27 resubmitted byte-identical (R13 bench was an infra failure:
// "MI355X container failed twice" -- no pytest/absmax/profile; zero signal).
// R27 rationale: R26 (cross-batch co-residency) regressed -- batches are
// statistically identical so their barriers run in lockstep; no overlap.
// Kernel body = R25's proven 289us fused (sort+skip+quartile-spread+
// interleave); the memset dispatch (~13us) is deleted: barrier counters
// live in zero-initialized .bss device globals; barrier is epoch-based
// monotonic: arriver's fetch_add old/SUBTGT = launch epoch (exact: each
// sub gets SUBTGT arrivals/launch, serialized launches), broadcast via
// LDS; all NSUB pollers wait for (epoch+1)*SUBTGT. No reset, replay-safe,
// first-launch-safe (.bss zero), 8-way parallel arrive chains.

#define BATCH 8
#define NPTS 2048
#define MPTS 2048
#define BLOCK 1024
#define ROWS 64
#define BLOCKS_PER_BATCH 32
#define NSUB 8
#define SUBTGT (BLOCKS_PER_BATCH / NSUB)   // 4
#define NSYNC 21
#define PAD 16                             // dwords per 64B line
#define SKIP_THR (-130.0f)
#define LOG2E 1.44269504088896340736f

__device__ unsigned ctrG[NSYNC * BATCH * NSUB * PAD];   // .bss, zero-init

__device__ __forceinline__ float fast_exp2(float x) {
  return __builtin_amdgcn_exp2f(x);     // v_exp_f32
}
__device__ __forceinline__ float fast_sqrt(float a) {
  return __builtin_amdgcn_sqrtf(a);     // v_sqrt_f32
}
__device__ __forceinline__ float packh2(float c, float r) {
  __half2 h = __halves2half2(__float2half_rn(c), __float2half_rn(r));
  return __builtin_bit_cast(float, h);
}

// ---- agent-scope coherent access helpers (bypass non-coherent XCD L2) ----
__device__ __forceinline__ float cohLoad(const float* p) {
  return __hip_atomic_load((float*)p, __ATOMIC_RELAXED,
                           __HIP_MEMORY_SCOPE_AGENT);
}
__device__ __forceinline__ void cohStore(float* p, float v) {
  __hip_atomic_store(p, v, __ATOMIC_RELAXED, __HIP_MEMORY_SCOPE_AGENT);
}

// Per-batch grid barrier, epoch-monotonic (no reset, no memset):
// arriver's fetch_add old encodes launch epoch k = old/SUBTGT (its sub has
// k*SUBTGT + a arrivals, a<SUBTGT). k broadcast via LDS; NSUB pollers wait
// for (k+1)*SUBTGT on their own 64B-line sub-counter. __syncthreads before
// arrive drains vmcnt(0) -> release; fence after poll -> acquire.
__device__ __forceinline__ void batch_barrier(unsigned* base, int bid) {
  __shared__ unsigned sEpoch;
  __syncthreads();
  if (threadIdx.x == 0) {
    unsigned old = __hip_atomic_fetch_add(base + (bid & (NSUB - 1)) * PAD, 1u,
                                          __ATOMIC_RELAXED,
                                          __HIP_MEMORY_SCOPE_AGENT);
    sEpoch = old / SUBTGT;
  }
  __syncthreads();                       // publish sEpoch
  if (threadIdx.x < NSUB) {
    unsigned target = (sEpoch + 1u) * SUBTGT;
    int guard = 0;
    while (__hip_atomic_load(base + threadIdx.x * PAD, __ATOMIC_RELAXED,
                             __HIP_MEMORY_SCOPE_AGENT) < target) {
      __builtin_amdgcn_s_sleep(2);
      if (++guard > (1 << 22)) break;
    }
  }
  asm volatile("" ::: "memory");
  __syncthreads();
}

// Wave-wide x-interval of per-lane values (min over lo, max over hi).
__device__ __forceinline__ void wave_interval(float& lo, float& hi) {
#pragma unroll
  for (int s = 1; s < 64; s <<= 1) {
    lo = fminf(lo, __shfl_xor(lo, s, 64));
    hi = fmaxf(hi, __shfl_xor(hi, s, 64));
  }
}

// Load 8 consecutive sorted points from LDS float4 array.
__device__ __forceinline__ void load8L(const float4* sA, int r0,
                                       float* x, float* y, float* z) {
#pragma unroll
  for (int j = 0; j < 8; ++j) {
    float4 v = sA[r0 + j];
    x[j] = v.x; y[j] = v.y; z[j] = v.z;
  }
}

// Transposed t1 sweep + owner fusion, LDS-resident sorted clouds.
// Owned m (quartile-spread): gm = (bslot + (m_idx>>4)*32)*16 + (m_idx&15).
// Wave spans 4 CONTIGUOUS sorted m's (tight interval). n iterated in 32
// chunks of 64 sorted points; wave-uniform skip via sTileN interval.
__device__ __forceinline__ void sweep2T_fuse(
    float nc, int tid, int bslot, const float* rsG, float* wpB,
    float4* sA, const float4* sP, const float2* sTileN, float* sRR) {
  // stage rs (sorted order) into sA[].w
  sA[tid].w = cohLoad(rsG + tid);
  sA[tid + 1024].w = cohLoad(rsG + tid + 1024);
  __syncthreads();
  const int m_idx = tid >> 4, c = tid & 15;
  const int gm = (bslot + (m_idx >> 4) * 32) * 16 + (m_idx & 15);
  const float4 pm = sP[gm];
  float mlo = pm.x, mhi = pm.x;
  wave_interval(mlo, mhi);
  float part = 0.f;
  for (int ch = 0; ch < 32; ++ch) {
    float2 tn = sTileN[ch];
    float gap = fmaxf(0.f, fmaxf(tn.x - mhi, mlo - tn.y));
    if (nc * gap * gap < SKIP_THR) continue;   // all 64 pairs underflow
    int nb = ch * 64 + c;
#pragma unroll
    for (int j = 0; j < 4; ++j) {
      float4 v = sA[nb + 16 * j];
      float dx = v.x - pm.x, dy = v.y - pm.y, dz = v.z - pm.z;
      float d2 = __builtin_fmaf(dx, dx, __builtin_fmaf(dy, dy, dz * dz));
      part = __builtin_fmaf(fast_exp2(nc * d2), v.w, part);
    }
  }
  part += __shfl_xor(part, 1, 64);
  part += __shfl_xor(part, 2, 64);
  part += __shfl_xor(part, 4, 64);
  part += __shfl_xor(part, 8, 64);
  if (c == 0) {
    float t1v = part;
    float rr = sRR[m_idx];
    float colsum = rr * t1v;
    float cs = fminf(rr / (colsum + 1e-9f), 1.0f);
    float ccv = rr * cs;
    float rn = fmaxf(rr - colsum * cs, 0.f);
    cohStore(wpB + gm, packh2(ccv, rn));
    sRR[m_idx] = rn;
  }
}

__global__ __launch_bounds__(BLOCK) void emd_fused_kernel(
    const float* __restrict__ xyz1, const float* __restrict__ xyz2,
    float* __restrict__ out, float* __restrict__ rowscaleG,
    float* __restrict__ wPack, float* __restrict__ R9acc,
    float* __restrict__ t9, float* __restrict__ outAcc) {
  extern __shared__ __align__(16) float4 sDyn[];
  float4* sA = sDyn;                       // sorted xyz1; w = rs (per sweep2T)
  float4* sP = sDyn + 2048;                // sorted xyz2; w = level payload
  unsigned* sKeyA = (unsigned*)(sDyn + 2048);        // aliases sP (sort phase)
  unsigned* sKeyB = ((unsigned*)(sDyn + 2048)) + 2048;

  __shared__ float sRedS[ROWS * 4];
  __shared__ float sRedC[ROWS * 4];
  __shared__ float sRedR[ROWS * 4];
  __shared__ float sCost[ROWS];
  __shared__ float sRowScale[ROWS];        // persistent across levels (local)
  __shared__ float sRemainL[ROWS];         // persistent across levels (local)
  __shared__ float sRR[ROWS];              // owner's rr slice (local)
  __shared__ float2 sTileM[128];           // 16-m-tile x-intervals (sorted)
  __shared__ float2 sTileN[32];            // 64-n-chunk x-intervals (sorted)

  const int tid = threadIdx.x;
  const int bid = blockIdx.x;
  const int b = bid >> 5;
  const int bslot = bid & 31;
  const bool desig = bslot == 0;
  const int wave = tid >> 6, lane = tid & 63;
  const int mq = wave & 3;                 // m-partition (stride-4 interleave)
  const int rh = wave >> 2;                // row-group (quartile-spread)
  const size_t bM = (size_t)b * MPTS;
  float costAcc = 0.f;                     // meaningful on tid==0
  // quartile-spread map: group g -> global sorted base index
#define GB(g) ((bslot + (g) * 32) * 16)

  float* rsG = rowscaleG + (size_t)b * NPTS;
  float* wpB = wPack + bM;
  const float* p1 = xyz1 + (size_t)b * NPTS * 3;
  const float* p2 = xyz2 + bM * 3;
#define CTRB(s) (ctrG + (size_t)(((s) * BATCH + b) * NSUB) * PAD)

  // ---- deterministic per-block sort of both clouds by x (identical in
  //      every block -> no cross-block traffic). Key = top-21 orderable
  //      float bits | 11-bit idx. ----
  for (int e = tid; e < 2048; e += 1024) {
    unsigned u1 = __builtin_bit_cast(unsigned, p1[e * 3]);
    u1 = (u1 & 0x80000000u) ? ~u1 : (u1 | 0x80000000u);
    sKeyA[e] = (u1 & 0xFFFFF800u) | (unsigned)e;
    unsigned u2 = __builtin_bit_cast(unsigned, p2[e * 3]);
    u2 = (u2 & 0x80000000u) ? ~u2 : (u2 | 0x80000000u);
    sKeyB[e] = (u2 & 0xFFFFF800u) | (unsigned)e;
  }
  for (unsigned k = 2; k <= 2048; k <<= 1) {
    for (unsigned j = k >> 1; j > 0; j >>= 1) {
      __syncthreads();
      for (int e = tid; e < 2048; e += 1024) {
        int l = e ^ (int)j;
        if (l > e) {
          bool up = ((e & (int)k) == 0);
          unsigned a = sKeyA[e], bv = sKeyA[l];
          if ((a > bv) == up) { sKeyA[e] = bv; sKeyA[l] = a; }
          unsigned a2 = sKeyB[e], b2 = sKeyB[l];
          if ((a2 > b2) == up) { sKeyB[e] = b2; sKeyB[l] = a2; }
        }
      }
    }
  }
  __syncthreads();
  {
    int iA0 = sKeyA[tid] & 2047, iA1 = sKeyA[tid + 1024] & 2047;
    int iB0 = sKeyB[tid] & 2047, iB1 = sKeyB[tid + 1024] & 2047;
    __syncthreads();                       // keys consumed; sP region free
    sA[tid]        = make_float4(p1[iA0*3], p1[iA0*3+1], p1[iA0*3+2], 0.f);
    sA[tid + 1024] = make_float4(p1[iA1*3], p1[iA1*3+1], p1[iA1*3+2], 0.f);
    sP[tid]        = make_float4(p2[iB0*3], p2[iB0*3+1], p2[iB0*3+2], 0.f);
    sP[tid + 1024] = make_float4(p2[iB1*3], p2[iB1*3+1], p2[iB1*3+2], 0.f);
  }
  if (tid < ROWS) sRR[tid] = 1.0f;
  if (desig && tid == 0) {
    cohStore(R9acc + b * PAD, 0.f);
    cohStore(t9 + b * PAD, 0.f);
    cohStore(outAcc + b * PAD, 0.f);
  }
  __syncthreads();
  // tile interval metadata (exact min/max; robust to truncated-key ties)
  if (tid < 128) {
    float lo = sP[tid * 16].x, hi = lo;
    for (int i = 1; i < 16; ++i) {
      float x = sP[tid * 16 + i].x;
      lo = fminf(lo, x); hi = fmaxf(hi, x);
    }
    sTileM[tid] = make_float2(lo, hi);
  } else if (tid < 160) {
    int t = tid - 128;
    float lo = sA[t * 64].x, hi = lo;
    for (int i = 1; i < 64; ++i) {
      float x = sA[t * 64 + i].x;
      lo = fminf(lo, x); hi = fmaxf(hi, x);
    }
    sTileN[t] = make_float2(lo, hi);
  }
  __syncthreads();

  // ---- A0: rowscale_0 (skip via interleaved 32-m chunks) ----
  const float nc0 = -16384.0f * LOG2E;
  {
    const int ph = lane >> 1, rg = lane & 1;
    float x1a[8], y1a[8], z1a[8], acc[8];
    load8L(sA, GB(rh) + rg * 8, x1a, y1a, z1a);
#pragma unroll
    for (int j = 0; j < 8; ++j) acc[j] = 0.f;
    float rlo = x1a[0], rhi = x1a[0];
#pragma unroll
    for (int j = 1; j < 8; ++j) {
      rlo = fminf(rlo, x1a[j]); rhi = fmaxf(rhi, x1a[j]);
    }
    wave_interval(rlo, rhi);
    for (int it = 0; it < 16; ++it) {
      int t2 = it * 4 + mq;               // 32-m chunk, stride-4 interleave
      float lo = sTileM[2 * t2].x, hi = sTileM[2 * t2 + 1].y;
      float gap = fmaxf(0.f, fmaxf(lo - rhi, rlo - hi));
      if (nc0 * gap * gap < SKIP_THR) continue;
      float4 v = sP[t2 * 32 + ph];
#pragma unroll
      for (int j = 0; j < 8; ++j) {
        float dx = x1a[j] - v.x, dy = y1a[j] - v.y, dz = z1a[j] - v.z;
        float d2 = __builtin_fmaf(dx, dx, __builtin_fmaf(dy, dy, dz * dz));
        acc[j] += fast_exp2(nc0 * d2);
      }
    }
#pragma unroll
    for (int j = 0; j < 8; ++j) {
      acc[j] += __shfl_xor(acc[j], 2, 64);
      acc[j] += __shfl_xor(acc[j], 4, 64);
      acc[j] += __shfl_xor(acc[j], 8, 64);
      acc[j] += __shfl_xor(acc[j], 16, 64);
      acc[j] += __shfl_xor(acc[j], 32, 64);
    }
    if (lane < 2) {
#pragma unroll
      for (int j = 0; j < 8; ++j)
        sRedS[(rh * 16 + rg * 8 + j) * 4 + mq] = acc[j];
    }
    __syncthreads();
    if (tid < ROWS) {
      float s = sRedS[tid * 4] + sRedS[tid * 4 + 1] + sRedS[tid * 4 + 2] +
                sRedS[tid * 4 + 3];
      float rs = 1.0f / (s + 1e-9f);
      sRowScale[tid] = rs;
      cohStore(rsG + GB(tid >> 4) + (tid & 15), rs);
    }
  }
  batch_barrier(CTRB(0), bid);          // rs_0 + init zeroes visible
  sweep2T_fuse(nc0, tid, bslot, rsG, wpB, sA, sP, sTileN, sRR);  // -> wPack_0
  batch_barrier(CTRB(1), bid);          // wPack_0 visible

  // ---- persistent CA row fragment (sorted coords from LDS) ----
  float x1[4], y1[4], z1[4];
  {
    int r0 = GB(rh) + (lane & 3) * 4;
#pragma unroll
    for (int j = 0; j < 4; ++j) {
      float4 v = sA[r0 + j];
      x1[j] = v.x; y1[j] = v.y; z1[j] = v.z;
    }
  }
  float rlo = fminf(fminf(x1[0], x1[1]), fminf(x1[2], x1[3]));
  float rhi = fmaxf(fmaxf(x1[0], x1[1]), fmaxf(x1[2], x1[3]));
  wave_interval(rlo, rhi);
  const int phc = lane >> 2, rgc = lane & 3;

  float nc2 = -4096.0f * LOG2E;   // levels[l+1]*LOG2E; exact /4 per level
  for (int l = 0; l < 9; ++l) {
    const bool LAST = (l == 8);
    // -- staging: sP[m].w = wPack_l[m] --
#pragma unroll
    for (int k = 0; k < 2; ++k) {
      int m = tid + k * 1024;
      sP[m].w = cohLoad(wpB + m);
    }
    __syncthreads();
    // -- sweep1: cost(l) + remainL + rowscale(l+1). e1 = e2^4 (exact).
    //    m-tiles stride-4 interleaved across mq; skip per 16-m tile. --
    float accS[4] = {0.f, 0.f, 0.f, 0.f};
    float accC[4] = {0.f, 0.f, 0.f, 0.f};
    float accR[4] = {0.f, 0.f, 0.f, 0.f};
    for (int it = 0; it < 32; ++it) {
      int t = it * 4 + mq;                // stride-4 interleave
      float2 tm = sTileM[t];
      float gap = fmaxf(0.f, fmaxf(tm.x - rhi, rlo - tm.y));
      if (nc2 * gap * gap < SKIP_THR) continue;
      float4 v = sP[t * 16 + phc];
      __half2 h = __builtin_bit_cast(__half2, v.w);
      float cc = __low2float(h);
      float rr = __high2float(h);
#pragma unroll
      for (int j = 0; j < 4; ++j) {
        float dx = x1[j] - v.x, dy = y1[j] - v.y, dz = z1[j] - v.z;
        float d2 = __builtin_fmaf(dx, dx, __builtin_fmaf(dy, dy, dz * dz));
        float sq = fast_sqrt(d2);
        float e2 = fast_exp2(nc2 * d2);
        float e2s = e2 * e2;
        float e1 = e2s * e2s;   // exp(levels[l]*d2); at LAST -> exp(-0.25 d2)
        float t2 = e1 * cc;
        accS[j] += t2;
        accC[j] = __builtin_fmaf(t2, sq, accC[j]);
        accR[j] = __builtin_fmaf(e2, rr, accR[j]);
      }
    }
#pragma unroll
    for (int j = 0; j < 4; ++j) {
      accS[j] += __shfl_xor(accS[j], 4, 64);
      accS[j] += __shfl_xor(accS[j], 8, 64);
      accS[j] += __shfl_xor(accS[j], 16, 64);
      accS[j] += __shfl_xor(accS[j], 32, 64);
      accC[j] += __shfl_xor(accC[j], 4, 64);
      accC[j] += __shfl_xor(accC[j], 8, 64);
      accC[j] += __shfl_xor(accC[j], 16, 64);
      accC[j] += __shfl_xor(accC[j], 32, 64);
      accR[j] += __shfl_xor(accR[j], 4, 64);
      accR[j] += __shfl_xor(accR[j], 8, 64);
      accR[j] += __shfl_xor(accR[j], 16, 64);
      accR[j] += __shfl_xor(accR[j], 32, 64);
    }
    if (lane < 4) {
#pragma unroll
      for (int j = 0; j < 4; ++j) {
        int row = rh * 16 + rgc * 4 + j;
        sRedS[row * 4 + mq] = accS[j];
        sRedC[row * 4 + mq] = accC[j];
        sRedR[row * 4 + mq] = accR[j];
      }
    }
    __syncthreads();
    if (tid < ROWS) {
      float S2 = sRedS[tid * 4] + sRedS[tid * 4 + 1] + sRedS[tid * 4 + 2] +
                 sRedS[tid * 4 + 3];
      float C = sRedC[tid * 4] + sRedC[tid * 4 + 1] + sRedC[tid * 4 + 2] +
                sRedC[tid * 4 + 3];
      float R = sRedR[tid * 4] + sRedR[tid * 4 + 1] + sRedR[tid * 4 + 2] +
                sRedR[tid * 4 + 3];
      if (LAST) R = cohLoad(R9acc + b * PAD);   // sum_m rr_9 (e == 1)
      float rs = sRowScale[tid];
      float rl = (l == 0) ? 1.0f : sRemainL[tid];
      float rlN = fmaxf(rl - rs * S2, 0.f);
      sRemainL[tid] = rlN;
      float rsN = rlN / (R + 1e-9f);
      sRowScale[tid] = rsN;
      if (!LAST) cohStore(rsG + GB(tid >> 4) + (tid & 15), rsN);
      sCost[tid] = rs * C;
    }
    __syncthreads();
    if (tid == 0) {
      float t = 0.f;
#pragma unroll
      for (int i = 0; i < ROWS; ++i) t += sCost[i];
      costAcc += t;
      if (LAST) {
        float r = 0.f;
#pragma unroll
        for (int i = 0; i < ROWS; ++i) r += sRowScale[i];
        atomicAdd(t9 + b * PAD, r);       // one per block, padded line
      }
    }
    if (!LAST) {
      batch_barrier(CTRB(2 + 2 * l), bid);    // rsN_{l+1} visible
      sweep2T_fuse(nc2, tid, bslot, rsG, wpB, sA, sP, sTileN, sRR);
      if (l == 7) {          // R9 = sum_m rr_9: block partial, one atomic
        __syncthreads();
        if (tid == 0) {
          float r9 = 0.f;
#pragma unroll
          for (int i = 0; i < ROWS; ++i) r9 += sRR[i];
          atomicAdd(R9acc + b * PAD, r9);
        }
      }
      batch_barrier(CTRB(3 + 2 * l), bid);    // wPack_{l+1} (+R9acc) visible
      nc2 *= 0.25f;
    }
  }
  batch_barrier(CTRB(18), bid);               // t9 complete

  // ---- C9 owner publish: w[m] from full-precision rr_9 + t9 ----
  if (tid < ROWS) {
    float rr = sRR[tid];
    float t1s = cohLoad(t9 + b * PAD);
    float w = rr * fminf(rr / (__builtin_fmaf(rr, t1s, 1e-9f)), 1.0f);
    cohStore(wpB + GB(tid >> 4) + (tid & 15), w); // full float (old C9 match)
  }
  batch_barrier(CTRB(19), bid);               // w visible

  // ---- C9 (lvl=0): cost with unscaled sorted coords (no skip: no exp) ----
  {
#pragma unroll
    for (int k = 0; k < 2; ++k) {
      int m = tid + k * 1024;
      sP[m].w = cohLoad(wpB + m);
    }
    __syncthreads();
    const int ph = lane >> 1, rg = lane & 1;
    float x1a[8], y1a[8], z1a[8], acc[8];
    load8L(sA, GB(rh) + rg * 8, x1a, y1a, z1a);
#pragma unroll
    for (int j = 0; j < 8; ++j) acc[j] = 0.f;
    const int mb = mq * 512 + ph;
#pragma unroll 2
    for (int it = 0; it < 16; ++it) {
      float4 v = sP[mb + it * 32];
#pragma unroll
      for (int j = 0; j < 8; ++j) {
        float dx = x1a[j] - v.x, dy = y1a[j] - v.y, dz = z1a[j] - v.z;
        float d2 = __builtin_fmaf(dx, dx, __builtin_fmaf(dy, dy, dz * dz));
        acc[j] = __builtin_fmaf(fast_sqrt(d2), v.w, acc[j]);
      }
    }
#pragma unroll
    for (int j = 0; j < 8; ++j) {
      acc[j] += __shfl_xor(acc[j], 2, 64);
      acc[j] += __shfl_xor(acc[j], 4, 64);
      acc[j] += __shfl_xor(acc[j], 8, 64);
      acc[j] += __shfl_xor(acc[j], 16, 64);
      acc[j] += __shfl_xor(acc[j], 32, 64);
    }
    if (lane < 2) {
#pragma unroll
      for (int j = 0; j < 8; ++j)
        sRedS[(rh * 16 + rg * 8 + j) * 4 + mq] = acc[j];
    }
    __syncthreads();
    if (tid < ROWS) {
      float C = sRedS[tid * 4] + sRedS[tid * 4 + 1] + sRedS[tid * 4 + 2] +
                sRedS[tid * 4 + 3];
      sCost[tid] = sRowScale[tid] * C;
    }
    __syncthreads();
    if (tid == 0) {
      float t = 0.f;
#pragma unroll
      for (int i = 0; i < ROWS; ++i) t += sCost[i];
      costAcc += t;
      atomicAdd(outAcc + b * PAD, costAcc);   // ONE atomic per block total
    }
  }
  batch_barrier(CTRB(20), bid);               // outAcc complete
  if (desig && tid == 0) out[b] = cohLoad(outAcc + b * PAD);
#undef CTRB
#undef GB
}

// ---------------------------------------------------------------------------
extern "C" void kernel_launch(void* const* d_in, const int* in_sizes, int n_in,
                              void* d_out, int out_size, void* d_ws, size_t ws_size,
                              hipStream_t stream) {
  const float* xyz1 = (const float*)d_in[0];
  const float* xyz2 = (const float*)d_in[1];
  float* out = (float*)d_out;
  float* ws = (float*)d_ws;

  const int BM = BATCH * MPTS;               // 16384
  float* rowscaleG = ws;                     // BM
  float* wPack     = ws + BM;                // BM
  float* R9acc     = ws + 2 * BM;            // BATCH*PAD
  float* t9        = ws + 2 * BM + BATCH * PAD;      // BATCH*PAD
  float* outAcc    = ws + 2 * BM + 2 * BATCH * PAD;  // BATCH*PAD

  static bool attrSet = false;
  if (!attrSet) {
    hipFuncSetAttribute((const void*)emd_fused_kernel,
                        hipFuncAttributeMaxDynamicSharedMemorySize, 65536);
    attrSet = true;
  }

  void* args[] = {(void*)&xyz1, (void*)&xyz2, (void*)&out, (void*)&rowscaleG,
                  (void*)&wPack, (void*)&R9acc, (void*)&t9, (void*)&outAcc};
  hipLaunchKernel((const void*)emd_fused_kernel,
                  dim3(BATCH * (NPTS / ROWS)), dim3(BLOCK), args,
                  65536, stream);
}

// Round 15
// 310.269 us; speedup vs baseline: 1.1439x; 1.0141x over previous
//
#include <hip/hip_runtime.h>
#include <hip/hip_fp16.h>

// EMD approx-match (auction) + match_cost, fully fused, ONE launch, NO memset.
// R29: compose the two PROVEN components. (1) R23 kernel body -- 256 blocks x
// 1024 threads, no sort/skip, static LDS, transposed-ownership t1, 21
// two-level barriers: fused 287us @ VALUBusy 78% (R28's sort+skip saves 34us
// of VALU issue but returns exactly ~34us as sort+variance stall: a wash,
// with more moving parts). (2) R27/R28 epoch-based .bss barrier (proven
// correct in R28): counters in zero-init device globals, arriver's
// fetch_add old/SUBTGT = launch epoch, broadcast via LDS, NSUB pollers wait
// (epoch+1)*SUBTGT -- deletes the memset dispatch (measured -4.4us in
// R25->R28). Expect: fused ~287, total ~306-310 (best of session).

#define BATCH 8
#define NPTS 2048
#define MPTS 2048
#define BLOCK 1024
#define ROWS 64
#define BLOCKS_PER_BATCH 32
#define NSUB 8
#define SUBTGT (BLOCKS_PER_BATCH / NSUB)   // 4
#define NSYNC 21
#define PAD 16                             // dwords per 64B line
#define SROW 17                            // padded staging row, float4s
#define LOG2E 1.44269504088896340736f

__device__ unsigned ctrG[NSYNC * BATCH * NSUB * PAD];   // .bss, zero-init

__device__ __forceinline__ float fast_exp2(float x) {
  return __builtin_amdgcn_exp2f(x);     // v_exp_f32
}
__device__ __forceinline__ float fast_sqrt(float a) {
  return __builtin_amdgcn_sqrtf(a);     // v_sqrt_f32
}
__device__ __forceinline__ float packh2(float c, float r) {
  __half2 h = __halves2half2(__float2half_rn(c), __float2half_rn(r));
  return __builtin_bit_cast(float, h);
}

// ---- agent-scope coherent access helpers (bypass non-coherent XCD L2) ----
__device__ __forceinline__ float cohLoad(const float* p) {
  return __hip_atomic_load((float*)p, __ATOMIC_RELAXED,
                           __HIP_MEMORY_SCOPE_AGENT);
}
__device__ __forceinline__ void cohStore(float* p, float v) {
  __hip_atomic_store(p, v, __ATOMIC_RELAXED, __HIP_MEMORY_SCOPE_AGENT);
}
__device__ __forceinline__ float4 cohLoad4(const float4* p) {
  const float* f = (const float*)p;
  return make_float4(cohLoad(f), cohLoad(f + 1), cohLoad(f + 2),
                     cohLoad(f + 3));
}

// LDS-only barrier: waits DS ops (lgkm) but leaves global/coherent loads
// (vmcnt) in flight. sched_barrier(0) pins hipcc from hoisting past it.
__device__ __forceinline__ void lds_barrier() {
  asm volatile("s_waitcnt lgkmcnt(0)" ::: "memory");
  __builtin_amdgcn_s_barrier();
  __builtin_amdgcn_sched_barrier(0);
}

// Per-batch grid barrier, epoch-monotonic (no reset, no memset):
// arriver's fetch_add old encodes launch epoch k = old/SUBTGT (its sub has
// k*SUBTGT + a arrivals, a<SUBTGT). k broadcast via LDS; NSUB pollers wait
// for (k+1)*SUBTGT on their own 64B-line sub-counter. __syncthreads before
// arrive drains vmcnt(0) -> release; fence after poll -> acquire.
__device__ __forceinline__ void batch_barrier(unsigned* base, int bid) {
  __shared__ unsigned sEpoch;
  __syncthreads();
  if (threadIdx.x == 0) {
    unsigned old = __hip_atomic_fetch_add(base + (bid & (NSUB - 1)) * PAD, 1u,
                                          __ATOMIC_RELAXED,
                                          __HIP_MEMORY_SCOPE_AGENT);
    sEpoch = old / SUBTGT;
  }
  __syncthreads();                       // publish sEpoch
  if (threadIdx.x < NSUB) {
    unsigned target = (sEpoch + 1u) * SUBTGT;
    int guard = 0;
    while (__hip_atomic_load(base + threadIdx.x * PAD, __ATOMIC_RELAXED,
                             __HIP_MEMORY_SCOPE_AGENT) < target) {
      __builtin_amdgcn_s_sleep(2);
      if (++guard > (1 << 22)) break;
    }
  }
  asm volatile("" ::: "memory");
  __syncthreads();
}

// Load 8 consecutive points (r0 multiple of 8) as 6 float4s (raw).
__device__ __forceinline__ void load8(const float4* q, int r0,
                                      float* x, float* y, float* z) {
  int b4 = (r0 >> 2) * 3;
  float4 q0 = q[b4], q1 = q[b4 + 1], q2 = q[b4 + 2];
  float4 q3 = q[b4 + 3], q4 = q[b4 + 4], q5 = q[b4 + 5];
  x[0] = q0.x; y[0] = q0.y; z[0] = q0.z;
  x[1] = q0.w; y[1] = q1.x; z[1] = q1.y;
  x[2] = q1.z; y[2] = q1.w; z[2] = q2.x;
  x[3] = q2.y; y[3] = q2.z; z[3] = q2.w;
  x[4] = q3.x; y[4] = q3.y; z[4] = q3.z;
  x[5] = q3.w; y[5] = q4.x; z[5] = q4.y;
  x[6] = q4.z; y[6] = q4.w; z[6] = q5.x;
  x[7] = q5.y; y[7] = q5.z; z[7] = q5.w;
}

// Transposed t1 sweep + owner fusion, 1024 threads. Thread t: m_idx = t>>4
// (owned m = t0+m_idx, 64 per block), c = t&15 covers points [c*16,c*16+16)
// of each 256-n chunk. 4 chunks staged per round into 4 padded buffers:
// quarter q = tid>>8 stages chunk 4r+q. 2 rounds. Register prefetch;
// lgkm-only barriers keep prefetch loads in flight.
__device__ __forceinline__ void sweep2T_fuse(
    float nc, int tid, int t0, const float4* q1, const float* rsG,
    float* wpB, const float4* sP, float4* sStage, float* sRR) {
  const int m_idx = tid >> 4, c = tid & 15;
  const float4 pm = sP[t0 + m_idx];
  const float4* rsg4 = (const float4*)rsG;
  const int rowb = c * SROW;
  const int tl = tid & 255;
  const int qtr = tid >> 8;            // quarter stages chunk 4r+qtr
  const bool isXyz = tl < 192;
  const int t = tl - 192;
  const int wIdx = qtr * (16 * SROW) +
                   (isXyz ? ((tl / 12) * SROW + (tl % 12))
                          : ((t >> 2) * SROW + 12 + (t & 3)));
  float4 v = isXyz ? q1[qtr * 192 + tl] : cohLoad4(rsg4 + qtr * 64 + t);
  float part = 0.f;
  for (int r = 0; r < 2; ++r) {
    lds_barrier();                  // prev round's ds_reads done
    sStage[wIdx] = v;               // auto-waits v (vmcnt dependency)
    if (r < 1) {
      int ch = 4 + qtr;
      v = isXyz ? q1[ch * 192 + tl] : cohLoad4(rsg4 + ch * 64 + t);
    }
    lds_barrier();                  // staged quad visible; prefetch in flight
#pragma unroll
    for (int h = 0; h < 4; ++h) {
      const float4* sB = sStage + h * (16 * SROW);
#pragma unroll
      for (int k = 0; k < 4; ++k) {
        float4 a  = sB[rowb + 3 * k];
        float4 bb = sB[rowb + 3 * k + 1];
        float4 cc = sB[rowb + 3 * k + 2];
        float4 r4 = sB[rowb + 12 + k];
        float px[4] = {a.x, a.w, bb.z, cc.y};
        float py[4] = {a.y, bb.x, bb.w, cc.z};
        float pz[4] = {a.z, bb.y, cc.x, cc.w};
        float rr[4] = {r4.x, r4.y, r4.z, r4.w};
#pragma unroll
        for (int j = 0; j < 4; ++j) {
          float dx = px[j] - pm.x, dy = py[j] - pm.y, dz = pz[j] - pm.z;
          float d2 = __builtin_fmaf(dx, dx, __builtin_fmaf(dy, dy, dz * dz));
          part = __builtin_fmaf(fast_exp2(nc * d2), rr[j], part);
        }
      }
    }
  }
  part += __shfl_xor(part, 1, 64);
  part += __shfl_xor(part, 2, 64);
  part += __shfl_xor(part, 4, 64);
  part += __shfl_xor(part, 8, 64);
  if (c == 0) {
    float t1v = part;
    float rr = sRR[m_idx];
    float colsum = rr * t1v;
    float cs = fminf(rr / (colsum + 1e-9f), 1.0f);
    float ccv = rr * cs;
    float rn = fmaxf(rr - colsum * cs, 0.f);
    cohStore(wpB + t0 + m_idx, packh2(ccv, rn));
    sRR[m_idx] = rn;
  }
}

__global__ __launch_bounds__(BLOCK) void emd_fused_kernel(
    const float* __restrict__ xyz1, const float* __restrict__ xyz2,
    float* __restrict__ out, float* __restrict__ rowscaleG,
    float* __restrict__ wPack, float* __restrict__ R9acc,
    float* __restrict__ t9, float* __restrict__ outAcc) {
  __shared__ float4 sP[MPTS];              // raw x2,y2,z2; w = level payload
  __shared__ float4 sStage[4 * 16 * SROW]; // sweep2T quad buffer
  __shared__ float sRedS[ROWS * 4];
  __shared__ float sRedC[ROWS * 4];
  __shared__ float sRedR[ROWS * 4];
  __shared__ float sCost[ROWS];
  __shared__ float sRowScale[ROWS];        // persistent across levels
  __shared__ float sRemainL[ROWS];         // persistent across levels
  __shared__ float sRR[ROWS];              // owner's rr slice, full precision

  const int tid = threadIdx.x;
  const int bid = blockIdx.x;
  const int b = bid >> 5;
  const int t0 = (bid & 31) * ROWS;
  const bool desig = (bid & 31) == 0;
  const int wave = tid >> 6, lane = tid & 63;
  const int mq = wave & 3;                 // m-quadrant
  const int rh = wave >> 2;                // row-quarter (0..3)
  const size_t bM = (size_t)b * MPTS;
  float costAcc = 0.f;                     // meaningful on tid==0

  float* rsG = rowscaleG + (size_t)b * NPTS;
  float* wpB = wPack + bM;
  const float4* q1 = (const float4*)(xyz1 + (size_t)b * NPTS * 3);
  const float4* q2 = (const float4*)(xyz2 + bM * 3);
#define CTRB(s) (ctrG + (size_t)(((s) * BATCH + b) * NSUB) * PAD)

  // ---- init: stage raw xyz2; rr_0 = 1; zero scalar accumulators ----
  if (tid < MPTS / 4) {
    int g = tid;
    float4 a = q2[3 * g], bb = q2[3 * g + 1], c = q2[3 * g + 2];
    sP[4 * g + 0] = make_float4(a.x, a.y, a.z, 0.f);
    sP[4 * g + 1] = make_float4(a.w, bb.x, bb.y, 0.f);
    sP[4 * g + 2] = make_float4(bb.z, bb.w, c.x, 0.f);
    sP[4 * g + 3] = make_float4(c.y, c.z, c.w, 0.f);
  }
  if (tid < ROWS) sRR[tid] = 1.0f;
  if (desig && tid == 0) {
    cohStore(R9acc + b * PAD, 0.f);
    cohStore(t9 + b * PAD, 0.f);
    cohStore(outAcc + b * PAD, 0.f);
  }
  __syncthreads();

  // ---- A0: rowscale_0 ----
  const float nc0 = -16384.0f * LOG2E;
  {
    const int ph = lane >> 1, rg = lane & 1;
    float x1a[8], y1a[8], z1a[8], acc[8];
    load8(q1, t0 + rh * 16 + rg * 8, x1a, y1a, z1a);
#pragma unroll
    for (int j = 0; j < 8; ++j) acc[j] = 0.f;
    const int mb = mq * 512 + ph;
#pragma unroll 2
    for (int it = 0; it < 16; ++it) {
      float4 v = sP[mb + it * 32];
#pragma unroll
      for (int j = 0; j < 8; ++j) {
        float dx = x1a[j] - v.x, dy = y1a[j] - v.y, dz = z1a[j] - v.z;
        float d2 = __builtin_fmaf(dx, dx, __builtin_fmaf(dy, dy, dz * dz));
        acc[j] += fast_exp2(nc0 * d2);
      }
    }
#pragma unroll
    for (int j = 0; j < 8; ++j) {
      acc[j] += __shfl_xor(acc[j], 2, 64);
      acc[j] += __shfl_xor(acc[j], 4, 64);
      acc[j] += __shfl_xor(acc[j], 8, 64);
      acc[j] += __shfl_xor(acc[j], 16, 64);
      acc[j] += __shfl_xor(acc[j], 32, 64);
    }
    if (lane < 2) {
#pragma unroll
      for (int j = 0; j < 8; ++j)
        sRedS[(rh * 16 + rg * 8 + j) * 4 + mq] = acc[j];
    }
    __syncthreads();
    if (tid < ROWS) {
      float s = sRedS[tid * 4] + sRedS[tid * 4 + 1] + sRedS[tid * 4 + 2] +
                sRedS[tid * 4 + 3];
      float rs = 1.0f / (s + 1e-9f);
      sRowScale[tid] = rs;
      cohStore(rsG + t0 + tid, rs);
    }
  }
  batch_barrier(CTRB(0), bid);          // rs_0 + init zeroes visible
  sweep2T_fuse(nc0, tid, t0, q1, rsG, wpB, sP, sStage, sRR);   // -> wPack_0
  batch_barrier(CTRB(1), bid);          // wPack_0 visible

  // ---- persistent CA row fragment (raw coords) ----
  float x1[4], y1[4], z1[4];
  {
    int b4 = ((t0 + rh * 16 + (lane & 3) * 4) >> 2) * 3;
    float4 a = q1[b4], bb = q1[b4 + 1], c = q1[b4 + 2];
    x1[0] = a.x;  y1[0] = a.y;  z1[0] = a.z;
    x1[1] = a.w;  y1[1] = bb.x; z1[1] = bb.y;
    x1[2] = bb.z; y1[2] = bb.w; z1[2] = c.x;
    x1[3] = c.y;  y1[3] = c.z;  z1[3] = c.w;
  }
  const int phc = lane >> 2, rgc = lane & 3;
  const int mbc = mq * 512 + phc;

  float nc2 = -4096.0f * LOG2E;   // levels[l+1]*LOG2E; exact /4 per level
  for (int l = 0; l < 9; ++l) {
    const bool LAST = (l == 8);
    // -- staging: sP[m].w = wPack_l[m], m = tid + 1024k --
#pragma unroll
    for (int k = 0; k < 2; ++k) {
      int m = tid + k * 1024;
      sP[m].w = cohLoad(wpB + m);
    }
    __syncthreads();
    // -- sweep1: cost(l) + remainL + rowscale(l+1). e1 = e2^4 (exact). --
    float accS[4] = {0.f, 0.f, 0.f, 0.f};
    float accC[4] = {0.f, 0.f, 0.f, 0.f};
    float accR[4] = {0.f, 0.f, 0.f, 0.f};
#pragma unroll 4
    for (int it = 0; it < 32; ++it) {
      float4 v = sP[mbc + it * 16];
      __half2 h = __builtin_bit_cast(__half2, v.w);
      float cc = __low2float(h);
      float rr = __high2float(h);
#pragma unroll
      for (int j = 0; j < 4; ++j) {
        float dx = x1[j] - v.x, dy = y1[j] - v.y, dz = z1[j] - v.z;
        float d2 = __builtin_fmaf(dx, dx, __builtin_fmaf(dy, dy, dz * dz));
        float sq = fast_sqrt(d2);
        float e2 = fast_exp2(nc2 * d2);
        float e2s = e2 * e2;
        float e1 = e2s * e2s;   // exp(levels[l]*d2); at LAST -> exp(-0.25 d2)
        float t = e1 * cc;
        accS[j] += t;
        accC[j] = __builtin_fmaf(t, sq, accC[j]);
        accR[j] = __builtin_fmaf(e2, rr, accR[j]);
      }
    }
#pragma unroll
    for (int j = 0; j < 4; ++j) {
      accS[j] += __shfl_xor(accS[j], 4, 64);
      accS[j] += __shfl_xor(accS[j], 8, 64);
      accS[j] += __shfl_xor(accS[j], 16, 64);
      accS[j] += __shfl_xor(accS[j], 32, 64);
      accC[j] += __shfl_xor(accC[j], 4, 64);
      accC[j] += __shfl_xor(accC[j], 8, 64);
      accC[j] += __shfl_xor(accC[j], 16, 64);
      accC[j] += __shfl_xor(accC[j], 32, 64);
      accR[j] += __shfl_xor(accR[j], 4, 64);
      accR[j] += __shfl_xor(accR[j], 8, 64);
      accR[j] += __shfl_xor(accR[j], 16, 64);
      accR[j] += __shfl_xor(accR[j], 32, 64);
    }
    if (lane < 4) {
#pragma unroll
      for (int j = 0; j < 4; ++j) {
        int row = rh * 16 + rgc * 4 + j;   // rgc == lane here
        sRedS[row * 4 + mq] = accS[j];
        sRedC[row * 4 + mq] = accC[j];
        sRedR[row * 4 + mq] = accR[j];
      }
    }
    __syncthreads();
    if (tid < ROWS) {
      float S2 = sRedS[tid * 4] + sRedS[tid * 4 + 1] + sRedS[tid * 4 + 2] +
                 sRedS[tid * 4 + 3];
      float C = sRedC[tid * 4] + sRedC[tid * 4 + 1] + sRedC[tid * 4 + 2] +
                sRedC[tid * 4 + 3];
      float R = sRedR[tid * 4] + sRedR[tid * 4 + 1] + sRedR[tid * 4 + 2] +
                sRedR[tid * 4 + 3];
      if (LAST) R = cohLoad(R9acc + b * PAD);   // sum_m rr_9 (e == 1)
      float rs = sRowScale[tid];
      float rl = (l == 0) ? 1.0f : sRemainL[tid];
      float rlN = fmaxf(rl - rs * S2, 0.f);
      sRemainL[tid] = rlN;
      float rsN = rlN / (R + 1e-9f);
      sRowScale[tid] = rsN;
      if (!LAST) cohStore(rsG + t0 + tid, rsN);
      sCost[tid] = rs * C;
    }
    __syncthreads();
    if (tid == 0) {
      float t = 0.f;
#pragma unroll
      for (int i = 0; i < ROWS; ++i) t += sCost[i];
      costAcc += t;
      if (LAST) {
        float r = 0.f;
#pragma unroll
        for (int i = 0; i < ROWS; ++i) r += sRowScale[i];
        atomicAdd(t9 + b * PAD, r);       // one per block, padded line
      }
    }
    if (!LAST) {
      batch_barrier(CTRB(2 + 2 * l), bid);    // rsN_{l+1} visible
      sweep2T_fuse(nc2, tid, t0, q1, rsG, wpB, sP, sStage, sRR);
      if (l == 7) {          // R9 = sum_m rr_9: block partial, one atomic
        __syncthreads();
        if (tid == 0) {
          float r9 = 0.f;
#pragma unroll
          for (int i = 0; i < ROWS; ++i) r9 += sRR[i];
          atomicAdd(R9acc + b * PAD, r9);
        }
      }
      batch_barrier(CTRB(3 + 2 * l), bid);    // wPack_{l+1} (+R9acc) visible
      nc2 *= 0.25f;
    }
  }
  batch_barrier(CTRB(18), bid);               // t9 complete

  // ---- C9 owner publish: w[m] from full-precision rr_9 + t9 ----
  if (tid < ROWS) {
    float rr = sRR[tid];
    float t1s = cohLoad(t9 + b * PAD);
    float w = rr * fminf(rr / (__builtin_fmaf(rr, t1s, 1e-9f)), 1.0f);
    cohStore(wpB + t0 + tid, w);              // full float (matches old C9)
  }
  batch_barrier(CTRB(19), bid);               // w visible

  // ---- C9 (lvl=0): cost with unscaled coords ----
  {
#pragma unroll
    for (int k = 0; k < 2; ++k) {
      int m = tid + k * 1024;
      sP[m].w = cohLoad(wpB + m);
    }
    __syncthreads();
    const int ph = lane >> 1, rg = lane & 1;
    float x1a[8], y1a[8], z1a[8], acc[8];
    load8(q1, t0 + rh * 16 + rg * 8, x1a, y1a, z1a);
#pragma unroll
    for (int j = 0; j < 8; ++j) acc[j] = 0.f;
    const int mb = mq * 512 + ph;
#pragma unroll 2
    for (int it = 0; it < 16; ++it) {
      float4 v = sP[mb + it * 32];
#pragma unroll
      for (int j = 0; j < 8; ++j) {
        float dx = x1a[j] - v.x, dy = y1a[j] - v.y, dz = z1a[j] - v.z;
        float d2 = __builtin_fmaf(dx, dx, __builtin_fmaf(dy, dy, dz * dz));
        acc[j] = __builtin_fmaf(fast_sqrt(d2), v.w, acc[j]);
      }
    }
#pragma unroll
    for (int j = 0; j < 8; ++j) {
      acc[j] += __shfl_xor(acc[j], 2, 64);
      acc[j] += __shfl_xor(acc[j], 4, 64);
      acc[j] += __shfl_xor(acc[j], 8, 64);
      acc[j] += __shfl_xor(acc[j], 16, 64);
      acc[j] += __shfl_xor(acc[j], 32, 64);
    }
    if (lane < 2) {
#pragma unroll
      for (int j = 0; j < 8; ++j)
        sRedS[(rh * 16 + rg * 8 + j) * 4 + mq] = acc[j];
    }
    __syncthreads();
    if (tid < ROWS) {
      float C = sRedS[tid * 4] + sRedS[tid * 4 + 1] + sRedS[tid * 4 + 2] +
                sRedS[tid * 4 + 3];
      sCost[tid] = sRowScale[tid] * C;
    }
    __syncthreads();
    if (tid == 0) {
      float t = 0.f;
#pragma unroll
      for (int i = 0; i < ROWS; ++i) t += sCost[i];
      costAcc += t;
      atomicAdd(outAcc + b * PAD, costAcc);   // ONE atomic per block total
    }
  }
  batch_barrier(CTRB(20), bid);               // outAcc complete
  if (desig && tid == 0) out[b] = cohLoad(outAcc + b * PAD);
#undef CTRB
}

// ---------------------------------------------------------------------------
extern "C" void kernel_launch(void* const* d_in, const int* in_sizes, int n_in,
                              void* d_out, int out_size, void* d_ws, size_t ws_size,
                              hipStream_t stream) {
  const float* xyz1 = (const float*)d_in[0];
  const float* xyz2 = (const float*)d_in[1];
  float* out = (float*)d_out;
  float* ws = (float*)d_ws;

  const int BM = BATCH * MPTS;               // 16384
  float* rowscaleG = ws;                     // BM
  float* wPack     = ws + BM;                // BM
  float* R9acc     = ws + 2 * BM;            // BATCH*PAD
  float* t9        = ws + 2 * BM + BATCH * PAD;      // BATCH*PAD
  float* outAcc    = ws + 2 * BM + 2 * BATCH * PAD;  // BATCH*PAD

  void* args[] = {(void*)&xyz1, (void*)&xyz2, (void*)&out, (void*)&rowscaleG,
                  (void*)&wPack, (void*)&R9acc, (void*)&t9, (void*)&outAcc};
  hipLaunchKernel((const void*)emd_fused_kernel,
                  dim3(BATCH * (NPTS / ROWS)), dim3(BLOCK), args, 0, stream);
}